// Round 7
// baseline (316.953 us; speedup 1.0000x reference)
//
#include <hip/hip_runtime.h>
#include <hip/hip_bf16.h>

#define BATCH 4
#define NPTS  8192
#define SPTS  2048
#define C1    128
#define C2    256
#define CIN   384   // C1+C2
#define H0    256
#define H1    128
#define NTOTF 32768.0f  // BATCH*NPTS

typedef __attribute__((ext_vector_type(8))) short bf16x8;
typedef __attribute__((ext_vector_type(4))) float f32x4;

__device__ __forceinline__ unsigned short f2bf(float x) {
  union { float f; unsigned u; } v; v.f = x;
  unsigned r = v.u + 0x7fff + ((v.u >> 16) & 1);   // RNE
  return (unsigned short)(r >> 16);
}
__device__ __forceinline__ float bf2f(unsigned short u) {
  union { unsigned u; float f; } v; v.u = ((unsigned)u) << 16; return v.f;
}

// ---------------- fused prep ----------------
// [0,512):    transpose points2 (B,C2,S) fp32 -> p2tb (B,S,C2) bf16
// [512,1024): pack points1 (B,C1,N) fp32 -> Xp[b][n][0..127] bf16 (stride CIN)
// [1024,1056): prepack xyz2 -> float4 (x,y,z,|c|^2)
// [1056,1184): weights fp32 -> bf16
// [1184]:     zero BN-stat accumulators (768 floats)
__global__ __launch_bounds__(256) void prep_kernel(
    const float* __restrict__ p2, unsigned short* __restrict__ p2tb,
    const float* __restrict__ xyz2, float4* __restrict__ xp,
    const float* __restrict__ w0, const float* __restrict__ w1,
    unsigned short* __restrict__ Wp,
    const float* __restrict__ p1, unsigned short* __restrict__ Xp,
    float* __restrict__ gstats) {
  __shared__ unsigned short shmem[64 * 136];
  int bid = blockIdx.x;
  int t = threadIdx.x;

  if (bid < 512) {  // ---- transpose p2 -> bf16 ----
    int b = bid >> 7, rem = bid & 127;
    int s0 = (rem >> 2) * 64, c0 = (rem & 3) * 64;
    const float* src = p2 + (size_t)b * C2 * SPTS;
    int ss = t & 63, cseg = t >> 6;
#pragma unroll
    for (int i = 0; i < 16; i++) {
      int cc = cseg + i * 4;
      shmem[ss * 72 + cc] = f2bf(src[(size_t)(c0 + cc) * SPTS + s0 + ss]);
    }
    __syncthreads();
    int s = t >> 2, chunk = t & 3;
    uint4 v0 = *(const uint4*)&shmem[s * 72 + chunk * 16];
    uint4 v1 = *(const uint4*)&shmem[s * 72 + chunk * 16 + 8];
    unsigned short* dst = p2tb + (size_t)b * SPTS * C2 + (size_t)(s0 + s) * C2 + c0 + chunk * 16;
    *(uint4*)dst = v0;
    *(uint4*)(dst + 8) = v1;
  } else if (bid < 1024) {  // ---- pack p1 -> Xp[...][0..C1) (stride CIN) ----
    int b2 = bid - 512;
    int b = b2 >> 7, n0 = (b2 & 127) * 64;
    int nn = t & 63, c4 = t >> 6;
#pragma unroll
    for (int i = 0; i < 32; i++) {
      int c = i * 4 + c4;
      shmem[nn * 136 + c] = f2bf(p1[((size_t)b * C1 + c) * NPTS + n0 + nn]);
    }
    __syncthreads();
    int n = t >> 2;
#pragma unroll
    for (int j = 0; j < 4; j++) {
      int ch = (t & 3) + j * 4;
      uint4 v = *(const uint4*)&shmem[n * 136 + ch * 8];
      *(uint4*)&Xp[((size_t)b * NPTS + n0 + n) * CIN + ch * 8] = v;
    }
  } else if (bid < 1056) {  // ---- prepack xyz2 ----
    int idx = (bid - 1024) * 256 + t;
    int b = idx >> 11, s = idx & (SPTS - 1);
    const float* x2 = xyz2 + (size_t)b * 3 * SPTS;
    float x = x2[s], y = x2[SPTS + s], z = x2[2 * SPTS + s];
    xp[idx] = make_float4(x, y, z, x * x + y * y + z * z);
  } else if (bid < 1184) {  // ---- pack weights ----
    int idx = ((bid - 1056) * 256 + t) * 4;
    const float* src = (idx < H0 * CIN) ? (w0 + idx) : (w1 + (idx - H0 * CIN));
    float4 v = *(const float4*)src;
    ushort4 o;
    o.x = f2bf(v.x); o.y = f2bf(v.y); o.z = f2bf(v.z); o.w = f2bf(v.w);
    *(ushort4*)(Wp + idx) = o;
  } else {  // ---- zero BN stat accumulators ----
#pragma unroll
    for (int j = 0; j < 3; j++) gstats[t + 256 * j] = 0.f;
  }
}

#define INS3(d, s, e0, e1, e2, j0, j1, j2)                        \
  {                                                               \
    bool lt0 = (d) < (e0), lt1 = (d) < (e1), lt2 = (d) < (e2);    \
    j2 = lt1 ? (j1) : (lt2 ? (s) : (j2));                         \
    j1 = lt0 ? (j0) : (lt1 ? (s) : (j1));                         \
    j0 = lt0 ? (s) : (j0);                                        \
    e2 = __builtin_amdgcn_fmed3f((d), (e1), (e2));                \
    e1 = __builtin_amdgcn_fmed3f((d), (e0), (e1));                \
    e0 = fminf((d), (e0));                                        \
  }

// ---------------- 3-NN search: 16 waves/block, 128-cand chunks, 2-stage merge ----------------
__global__ __launch_bounds__(1024) void knn_kernel(
    const float* __restrict__ xyz1, const float4* __restrict__ xp,
    int* __restrict__ nidx, float* __restrict__ nw) {
  int b = blockIdx.y;
  int t = threadIdx.x;
  int lane = t & 63;
  int w = __builtin_amdgcn_readfirstlane(t >> 6);
  int n = blockIdx.x * 64 + lane;
  const float* x1 = xyz1 + (size_t)b * 3 * NPTS;
  float px = x1[n], py = x1[NPTS + n], pz = x1[2 * NPTS + n];

  const int CHUNK = SPTS / 16;
  int sbase = w * CHUNK;
  const float4* cp = xp + (size_t)b * SPTS + sbase;

  float d0 = 3e38f, d1 = 3e38f, d2 = 3e38f;
  int i0 = 0, i1 = 0, i2 = 0;
#pragma unroll 8
  for (int j = 0; j < CHUNK; j++) {
    float4 c = cp[j];
    float qc = fmaf(py, c.y, px * c.x);
    qc = fmaf(pz, c.z, qc);
    float d = fmaf(-2.f, qc, c.w);
    int s = sbase + j;
    INS3(d, s, d0, d1, d2, i0, i1, i2);
  }

  __shared__ float dsh[16][64][3];
  __shared__ int   ish[16][64][3];
  dsh[w][lane][0] = d0; dsh[w][lane][1] = d1; dsh[w][lane][2] = d2;
  ish[w][lane][0] = i0; ish[w][lane][1] = i1; ish[w][lane][2] = i2;
  __syncthreads();

  if (t < 256) {
    int g = t >> 6, q = t & 63;
    float e0 = 3e38f, e1 = 3e38f, e2 = 3e38f;
    int j0 = 0, j1 = 0, j2 = 0;
#pragma unroll
    for (int c = 0; c < 4; c++) {
#pragma unroll
      for (int k = 0; k < 3; k++) {
        float d = dsh[4 * g + c][q][k];
        int s = ish[4 * g + c][q][k];
        INS3(d, s, e0, e1, e2, j0, j1, j2);
      }
    }
    dsh[4 * g][q][0] = e0; dsh[4 * g][q][1] = e1; dsh[4 * g][q][2] = e2;
    ish[4 * g][q][0] = j0; ish[4 * g][q][1] = j1; ish[4 * g][q][2] = j2;
  }
  __syncthreads();

  if (t < 64) {
    float e0 = 3e38f, e1 = 3e38f, e2 = 3e38f;
    int j0 = 0, j1 = 0, j2 = 0;
#pragma unroll
    for (int c = 0; c < 4; c++) {
#pragma unroll
      for (int k = 0; k < 3; k++) {
        float d = dsh[4 * c][t][k];
        int s = ish[4 * c][t][k];
        INS3(d, s, e0, e1, e2, j0, j1, j2);
      }
    }
    float qq = px * px + py * py + pz * pz;
    float r0 = 1.f / (e0 + qq + 1e-8f);
    float r1 = 1.f / (e1 + qq + 1e-8f);
    float r2 = 1.f / (e2 + qq + 1e-8f);
    float rs = 1.f / (r0 + r1 + r2);
    int base = (b * NPTS + n) * 3;
    nidx[base + 0] = j0; nidx[base + 1] = j1; nidx[base + 2] = j2;
    nw[base + 0] = r0 * rs; nw[base + 1] = r1 * rs; nw[base + 2] = r2 * rs;
  }
}

// ---------------- interpolation (bf16 gather, standalone) -> Xp[b][n][128..383] ----------------
// NOTE R6 lesson: random-row gathers live HERE (16k blocks of latency-hiding
// parallelism), never inside a barrier-locked GEMM K-loop.
__global__ __launch_bounds__(256) void interp_kernel(
    const unsigned short* __restrict__ p2tb, const int* __restrict__ nidx,
    const float* __restrict__ nw, unsigned short* __restrict__ Xp) {
  const int PTS = 8;
  int bid = blockIdx.x;
  int b = bid / (NPTS / PTS);
  int p0 = (bid % (NPTS / PTS)) * PTS;
  int c = threadIdx.x;
  const unsigned short* base = p2tb + (size_t)b * SPTS * C2;
#pragma unroll
  for (int k = 0; k < PTS; k++) {
    int p = p0 + k;
    int ib = (b * NPTS + p) * 3;
    int i0 = nidx[ib], i1 = nidx[ib + 1], i2 = nidx[ib + 2];
    float w0v = nw[ib], w1v = nw[ib + 1], w2v = nw[ib + 2];
    float v = w0v * bf2f(base[(size_t)i0 * C2 + c]) +
              w1v * bf2f(base[(size_t)i1 * C2 + c]) +
              w2v * bf2f(base[(size_t)i2 * C2 + c]);
    Xp[((size_t)b * NPTS + p) * CIN + C1 + c] = f2bf(v);
  }
}

// ---------------- MFMA GEMM (m97 structure) + BN stats in epilogue ----------------
// Y[b,m,n] = sum_k A[m,k]*X[b,n,k] + bias[m]; atomically accumulates
// per-channel sum/sumsq into gsum/gsq.
template <int MT, int KD, bool OUT_BF16>
__global__ __launch_bounds__(256) void mfma_gemm_kernel(
    const unsigned short* __restrict__ A, const unsigned short* __restrict__ X,
    const float* __restrict__ bias, void* __restrict__ Yv,
    float* __restrict__ gsum, float* __restrict__ gsq) {
  __shared__ unsigned short As[128 * 32];
  __shared__ unsigned short Bs[128 * 32];
  int b = blockIdx.z;
  int n0 = blockIdx.x * 128;
  int o0 = blockIdx.y * 128;
  int t = threadIdx.x;
  int lane = t & 63;
  int w = __builtin_amdgcn_readfirstlane(t >> 6);
  int mhalf = (w & 1) * 64, nhalf = (w >> 1) * 64;
  const unsigned short* Xb = X + (size_t)b * NPTS * KD;

  f32x4 acc[4][4] = {};
  int rA = lane >> 2;
  int cofs = (lane & 3) * 8;

  for (int k0 = 0; k0 < KD; k0 += 32) {
#pragma unroll
    for (int q = 0; q < 2; q++) {
      int r0 = w * 32 + q * 16;
      const unsigned short* ga = A + (size_t)(o0 + r0 + rA) * KD + k0 + cofs;
      __builtin_amdgcn_global_load_lds(
          (const __attribute__((address_space(1))) void*)ga,
          (__attribute__((address_space(3))) void*)(As + r0 * 32), 16, 0, 0);
      const unsigned short* gb = Xb + (size_t)(n0 + r0 + rA) * KD + k0 + cofs;
      __builtin_amdgcn_global_load_lds(
          (const __attribute__((address_space(1))) void*)gb,
          (__attribute__((address_space(3))) void*)(Bs + r0 * 32), 16, 0, 0);
    }
    __syncthreads();

    bf16x8 af[4], bfr[4];
    int mi = lane & 15, kq = (lane >> 4) * 8;
#pragma unroll
    for (int i = 0; i < 4; i++) {
      af[i]  = *(const bf16x8*)(As + (mhalf + i * 16 + mi) * 32 + kq);
      bfr[i] = *(const bf16x8*)(Bs + (nhalf + i * 16 + mi) * 32 + kq);
    }
#pragma unroll
    for (int mt = 0; mt < 4; mt++)
#pragma unroll
      for (int nt = 0; nt < 4; nt++)
        acc[mt][nt] = __builtin_amdgcn_mfma_f32_16x16x32_bf16(
            af[mt], bfr[nt], acc[mt][nt], 0, 0, 0);
    __syncthreads();
  }

  // epilogue: write + per-channel sum/sumsq (16-lane xor-reduce over n, then atomic)
  int mi = lane & 15;
  int rq = (lane >> 4) * 4;
#pragma unroll
  for (int mt = 0; mt < 4; mt++) {
#pragma unroll
    for (int r = 0; r < 4; r++) {
      int m = o0 + mhalf + mt * 16 + rq + r;
      float bv = bias[m];
      float sv = 0.f, sq = 0.f;
#pragma unroll
      for (int nt = 0; nt < 4; nt++) {
        int n = n0 + nhalf + nt * 16 + mi;
        float v = acc[mt][nt][r] + bv;
        if constexpr (OUT_BF16) {
          unsigned short* Y = (unsigned short*)Yv + (size_t)b * MT * NPTS;
          Y[(size_t)m * NPTS + n] = f2bf(v);
        } else {
          float* Y = (float*)Yv + (size_t)b * MT * NPTS;
          Y[(size_t)m * NPTS + n] = v;
        }
        sv += v; sq += v * v;
      }
#pragma unroll
      for (int msk = 1; msk < 16; msk <<= 1) {
        sv += __shfl_xor(sv, msk);
        sq += __shfl_xor(sq, msk);
      }
      if (mi == 0) { atomicAdd(&gsum[m], sv); atomicAdd(&gsq[m], sq); }
    }
  }
}

// ---------------- BN0 apply + ReLU + transpose (inline stats finalize) ----------------
__global__ __launch_bounds__(256) void bn0_apply_kernel(
    const unsigned short* __restrict__ Y0, const float* __restrict__ gsum,
    const float* __restrict__ gsq, const float* __restrict__ gamma,
    const float* __restrict__ beta, unsigned short* __restrict__ X1) {
  __shared__ unsigned short tile[64][80];
  int b = blockIdx.z, o0 = blockIdx.y * 64, n0 = blockIdx.x * 64;
  int t = threadIdx.x;
  int nn = t & 63, o4 = t >> 6;
  const float inv = 1.f / NTOTF;
#pragma unroll
  for (int i = 0; i < 16; i++) {
    int o = i * 4 + o4;
    int oc = o0 + o;
    float mean = gsum[oc] * inv;
    float var = gsq[oc] * inv - mean * mean;
    float ia = gamma[oc] * rsqrtf(var + 1e-5f);
    float sh = beta[oc] - mean * ia;
    float v = bf2f(Y0[((size_t)b * H0 + oc) * NPTS + n0 + nn]);
    v = fmaxf(v * ia + sh, 0.f);
    tile[nn][o] = f2bf(v);
  }
  __syncthreads();
  int n = t >> 2;
#pragma unroll
  for (int j = 0; j < 2; j++) {
    int ch = (t & 3) + j * 4;
    uint4 v = *(const uint4*)&tile[n][ch * 8];
    *(uint4*)&X1[((size_t)b * NPTS + n0 + n) * H0 + o0 + ch * 8] = v;
  }
}

// ---------------- final BN+ReLU in-place on d_out (inline stats finalize) ----------------
__global__ __launch_bounds__(256) void bn_apply_kernel(
    float* __restrict__ Y, const float* __restrict__ gsum, const float* __restrict__ gsq,
    const float* __restrict__ gamma, const float* __restrict__ beta) {
  int idx = blockIdx.x * 256 + threadIdx.x;
  int i = idx * 4;
  int c = (i >> 13) & (H1 - 1);
  const float inv = 1.f / NTOTF;
  float mean = gsum[c] * inv;
  float var = gsq[c] * inv - mean * mean;
  float ia = gamma[c] * rsqrtf(var + 1e-5f);
  float sh = beta[c] - mean * ia;
  float4 v = *(float4*)(Y + i);
  v.x = fmaxf(v.x * ia + sh, 0.f);
  v.y = fmaxf(v.y * ia + sh, 0.f);
  v.z = fmaxf(v.z * ia + sh, 0.f);
  v.w = fmaxf(v.w * ia + sh, 0.f);
  *(float4*)(Y + i) = v;
}

extern "C" void kernel_launch(void* const* d_in, const int* in_sizes, int n_in,
                              void* d_out, int out_size, void* d_ws, size_t ws_size,
                              hipStream_t stream) {
  const float* xyz1    = (const float*)d_in[0];
  const float* xyz2    = (const float*)d_in[1];
  const float* points1 = (const float*)d_in[2];
  const float* points2 = (const float*)d_in[3];
  const float* w0      = (const float*)d_in[4];
  const float* b0      = (const float*)d_in[5];
  const float* gamma0  = (const float*)d_in[6];
  const float* beta0   = (const float*)d_in[7];
  const float* w1      = (const float*)d_in[8];
  const float* b1      = (const float*)d_in[9];
  const float* gamma1  = (const float*)d_in[10];
  const float* beta1   = (const float*)d_in[11];
  float* out = (float*)d_out;

  char* ws = (char*)d_ws;
  unsigned short* p2tb = (unsigned short*)ws;  ws += (size_t)BATCH * SPTS * C2 * 2;   // 4.2 MB
  unsigned short* Xp = (unsigned short*)ws;    ws += (size_t)BATCH * NPTS * CIN * 2;  // 25.2 MB
  unsigned short* Y0 = (unsigned short*)ws;    ws += (size_t)BATCH * H0 * NPTS * 2;   // 16.8 MB
  unsigned short* X1 = (unsigned short*)ws;    ws += (size_t)BATCH * NPTS * H0 * 2;   // 16.8 MB
  unsigned short* Wp = (unsigned short*)ws;    ws += (size_t)(H0 * CIN + H1 * H0) * 2;
  int* nidx = (int*)ws;                        ws += (size_t)BATCH * NPTS * 3 * 4;
  float* nw = (float*)ws;                      ws += (size_t)BATCH * NPTS * 3 * 4;
  float4* xyz2p = (float4*)(((uintptr_t)ws + 15) & ~(uintptr_t)15);
  ws = (char*)xyz2p + (size_t)BATCH * SPTS * 16;
  float* gstats = (float*)ws;                  ws += 768 * 4;
  float* gsum0 = gstats;        // 256
  float* gsq0  = gstats + 256;  // 256
  float* gsum1 = gstats + 512;  // 128
  float* gsq1  = gstats + 640;  // 128
  (void)ws_size; (void)in_sizes; (void)n_in; (void)out_size;

  prep_kernel<<<dim3(1185), 256, 0, stream>>>(points2, p2tb, xyz2, xyz2p,
                                              w0, w1, Wp, points1, Xp, gstats);
  knn_kernel<<<dim3(NPTS / 64, BATCH), 1024, 0, stream>>>(xyz1, xyz2p, nidx, nw);
  interp_kernel<<<dim3(BATCH * NPTS / 8), 256, 0, stream>>>(p2tb, nidx, nw, Xp);

  mfma_gemm_kernel<H0, CIN, true><<<dim3(NPTS / 128, H0 / 128, BATCH), 256, 0, stream>>>(
      Wp, Xp, b0, Y0, gsum0, gsq0);
  bn0_apply_kernel<<<dim3(NPTS / 64, H0 / 64, BATCH), 256, 0, stream>>>(
      Y0, gsum0, gsq0, gamma0, beta0, X1);
  mfma_gemm_kernel<H1, H0, false><<<dim3(NPTS / 128, 1, BATCH), 256, 0, stream>>>(
      Wp + H0 * CIN, X1, b1, out, gsum1, gsq1);
  bn_apply_kernel<<<dim3(BATCH * H1 * NPTS / 1024), 256, 0, stream>>>(
      out, gsum1, gsq1, gamma1, beta1);
}

// Round 8
// 203.745 us; speedup vs baseline: 1.5556x; 1.5556x over previous
//
#include <hip/hip_runtime.h>
#include <hip/hip_bf16.h>

#define BATCH 4
#define NPTS  8192
#define SPTS  2048
#define C1    128
#define C2    256
#define CIN   384   // C1+C2
#define H0    256
#define H1    128
#define NTOTF 32768.0f  // BATCH*NPTS
#define NPART 512       // stat partials per channel: b(4) x nx(64) x nhalf(2)

typedef __attribute__((ext_vector_type(8))) short bf16x8;
typedef __attribute__((ext_vector_type(4))) float f32x4;

__device__ __forceinline__ unsigned short f2bf(float x) {
  union { float f; unsigned u; } v; v.f = x;
  unsigned r = v.u + 0x7fff + ((v.u >> 16) & 1);   // RNE
  return (unsigned short)(r >> 16);
}
__device__ __forceinline__ float bf2f(unsigned short u) {
  union { unsigned u; float f; } v; v.u = ((unsigned)u) << 16; return v.f;
}

// ---------------- fused prep ----------------
// [0,512):    transpose points2 (B,C2,S) fp32 -> p2tb (B,S,C2) bf16
// [512,1024): pack points1 (B,C1,N) fp32 -> Xp[b][n][0..127] bf16 (stride CIN)
// [1024,1056): prepack xyz2 -> float4 (x,y,z,|c|^2)
// [1056,1184): weights fp32 -> bf16
__global__ __launch_bounds__(256) void prep_kernel(
    const float* __restrict__ p2, unsigned short* __restrict__ p2tb,
    const float* __restrict__ xyz2, float4* __restrict__ xp,
    const float* __restrict__ w0, const float* __restrict__ w1,
    unsigned short* __restrict__ Wp,
    const float* __restrict__ p1, unsigned short* __restrict__ Xp) {
  __shared__ unsigned short shmem[64 * 136];
  int bid = blockIdx.x;
  int t = threadIdx.x;

  if (bid < 512) {  // ---- transpose p2 -> bf16 ----
    int b = bid >> 7, rem = bid & 127;
    int s0 = (rem >> 2) * 64, c0 = (rem & 3) * 64;
    const float* src = p2 + (size_t)b * C2 * SPTS;
    int ss = t & 63, cseg = t >> 6;
#pragma unroll
    for (int i = 0; i < 16; i++) {
      int cc = cseg + i * 4;
      shmem[ss * 72 + cc] = f2bf(src[(size_t)(c0 + cc) * SPTS + s0 + ss]);
    }
    __syncthreads();
    int s = t >> 2, chunk = t & 3;
    uint4 v0 = *(const uint4*)&shmem[s * 72 + chunk * 16];
    uint4 v1 = *(const uint4*)&shmem[s * 72 + chunk * 16 + 8];
    unsigned short* dst = p2tb + (size_t)b * SPTS * C2 + (size_t)(s0 + s) * C2 + c0 + chunk * 16;
    *(uint4*)dst = v0;
    *(uint4*)(dst + 8) = v1;
  } else if (bid < 1024) {  // ---- pack p1 -> Xp[...][0..C1) (stride CIN) ----
    int b2 = bid - 512;
    int b = b2 >> 7, n0 = (b2 & 127) * 64;
    int nn = t & 63, c4 = t >> 6;
#pragma unroll
    for (int i = 0; i < 32; i++) {
      int c = i * 4 + c4;
      shmem[nn * 136 + c] = f2bf(p1[((size_t)b * C1 + c) * NPTS + n0 + nn]);
    }
    __syncthreads();
    int n = t >> 2;
#pragma unroll
    for (int j = 0; j < 4; j++) {
      int ch = (t & 3) + j * 4;
      uint4 v = *(const uint4*)&shmem[n * 136 + ch * 8];
      *(uint4*)&Xp[((size_t)b * NPTS + n0 + n) * CIN + ch * 8] = v;
    }
  } else if (bid < 1056) {  // ---- prepack xyz2 ----
    int idx = (bid - 1024) * 256 + t;
    int b = idx >> 11, s = idx & (SPTS - 1);
    const float* x2 = xyz2 + (size_t)b * 3 * SPTS;
    float x = x2[s], y = x2[SPTS + s], z = x2[2 * SPTS + s];
    xp[idx] = make_float4(x, y, z, x * x + y * y + z * z);
  } else {  // ---- pack weights ----
    int idx = ((bid - 1056) * 256 + t) * 4;
    const float* src = (idx < H0 * CIN) ? (w0 + idx) : (w1 + (idx - H0 * CIN));
    float4 v = *(const float4*)src;
    ushort4 o;
    o.x = f2bf(v.x); o.y = f2bf(v.y); o.z = f2bf(v.z); o.w = f2bf(v.w);
    *(ushort4*)(Wp + idx) = o;
  }
}

#define INS3(d, s, e0, e1, e2, j0, j1, j2)                        \
  {                                                               \
    bool lt0 = (d) < (e0), lt1 = (d) < (e1), lt2 = (d) < (e2);    \
    j2 = lt1 ? (j1) : (lt2 ? (s) : (j2));                         \
    j1 = lt0 ? (j0) : (lt1 ? (s) : (j1));                         \
    j0 = lt0 ? (s) : (j0);                                        \
    e2 = __builtin_amdgcn_fmed3f((d), (e1), (e2));                \
    e1 = __builtin_amdgcn_fmed3f((d), (e0), (e1));                \
    e0 = fminf((d), (e0));                                        \
  }

// ---------------- 3-NN search: 16 waves/block, 128-cand chunks, 2-stage merge ----------------
__global__ __launch_bounds__(1024) void knn_kernel(
    const float* __restrict__ xyz1, const float4* __restrict__ xp,
    int* __restrict__ nidx, float* __restrict__ nw) {
  int b = blockIdx.y;
  int t = threadIdx.x;
  int lane = t & 63;
  int w = __builtin_amdgcn_readfirstlane(t >> 6);
  int n = blockIdx.x * 64 + lane;
  const float* x1 = xyz1 + (size_t)b * 3 * NPTS;
  float px = x1[n], py = x1[NPTS + n], pz = x1[2 * NPTS + n];

  const int CHUNK = SPTS / 16;
  int sbase = w * CHUNK;
  const float4* cp = xp + (size_t)b * SPTS + sbase;

  float d0 = 3e38f, d1 = 3e38f, d2 = 3e38f;
  int i0 = 0, i1 = 0, i2 = 0;
#pragma unroll 8
  for (int j = 0; j < CHUNK; j++) {
    float4 c = cp[j];
    float qc = fmaf(py, c.y, px * c.x);
    qc = fmaf(pz, c.z, qc);
    float d = fmaf(-2.f, qc, c.w);
    int s = sbase + j;
    INS3(d, s, d0, d1, d2, i0, i1, i2);
  }

  __shared__ float dsh[16][64][3];
  __shared__ int   ish[16][64][3];
  dsh[w][lane][0] = d0; dsh[w][lane][1] = d1; dsh[w][lane][2] = d2;
  ish[w][lane][0] = i0; ish[w][lane][1] = i1; ish[w][lane][2] = i2;
  __syncthreads();

  if (t < 256) {
    int g = t >> 6, q = t & 63;
    float e0 = 3e38f, e1 = 3e38f, e2 = 3e38f;
    int j0 = 0, j1 = 0, j2 = 0;
#pragma unroll
    for (int c = 0; c < 4; c++) {
#pragma unroll
      for (int k = 0; k < 3; k++) {
        float d = dsh[4 * g + c][q][k];
        int s = ish[4 * g + c][q][k];
        INS3(d, s, e0, e1, e2, j0, j1, j2);
      }
    }
    dsh[4 * g][q][0] = e0; dsh[4 * g][q][1] = e1; dsh[4 * g][q][2] = e2;
    ish[4 * g][q][0] = j0; ish[4 * g][q][1] = j1; ish[4 * g][q][2] = j2;
  }
  __syncthreads();

  if (t < 64) {
    float e0 = 3e38f, e1 = 3e38f, e2 = 3e38f;
    int j0 = 0, j1 = 0, j2 = 0;
#pragma unroll
    for (int c = 0; c < 4; c++) {
#pragma unroll
      for (int k = 0; k < 3; k++) {
        float d = dsh[4 * c][t][k];
        int s = ish[4 * c][t][k];
        INS3(d, s, e0, e1, e2, j0, j1, j2);
      }
    }
    float qq = px * px + py * py + pz * pz;
    float r0 = 1.f / (e0 + qq + 1e-8f);
    float r1 = 1.f / (e1 + qq + 1e-8f);
    float r2 = 1.f / (e2 + qq + 1e-8f);
    float rs = 1.f / (r0 + r1 + r2);
    int base = (b * NPTS + n) * 3;
    nidx[base + 0] = j0; nidx[base + 1] = j1; nidx[base + 2] = j2;
    nw[base + 0] = r0 * rs; nw[base + 1] = r1 * rs; nw[base + 2] = r2 * rs;
  }
}

// ---------------- interpolation (bf16 gather, standalone) -> Xp[b][n][128..383] ----------------
__global__ __launch_bounds__(256) void interp_kernel(
    const unsigned short* __restrict__ p2tb, const int* __restrict__ nidx,
    const float* __restrict__ nw, unsigned short* __restrict__ Xp) {
  const int PTS = 8;
  int bid = blockIdx.x;
  int b = bid / (NPTS / PTS);
  int p0 = (bid % (NPTS / PTS)) * PTS;
  int c = threadIdx.x;
  const unsigned short* base = p2tb + (size_t)b * SPTS * C2;
#pragma unroll
  for (int k = 0; k < PTS; k++) {
    int p = p0 + k;
    int ib = (b * NPTS + p) * 3;
    int i0 = nidx[ib], i1 = nidx[ib + 1], i2 = nidx[ib + 2];
    float w0v = nw[ib], w1v = nw[ib + 1], w2v = nw[ib + 2];
    float v = w0v * bf2f(base[(size_t)i0 * C2 + c]) +
              w1v * bf2f(base[(size_t)i1 * C2 + c]) +
              w2v * bf2f(base[(size_t)i2 * C2 + c]);
    Xp[((size_t)b * NPTS + p) * CIN + C1 + c] = f2bf(v);
  }
}

// ---------------- GEMM1: writes X1 (B,N,H0) bf16 TRANSPOSED + partial stats ----------------
// X1raw[b][n][m] = sum_k W0[m,k]*Xp[b,n,k] + b0[m]
// Stats: per-wave partial sums to gp0s/gp0q[ch][pidx] -- plain stores, NO atomics (R7 lesson).
__global__ __launch_bounds__(256) void gemm1_kernel(
    const unsigned short* __restrict__ A, const unsigned short* __restrict__ X,
    const float* __restrict__ bias, unsigned short* __restrict__ X1,
    float* __restrict__ gp0s, float* __restrict__ gp0q) {
  __shared__ unsigned short As[128 * 32];
  __shared__ unsigned short Bs[128 * 32];
  int b = blockIdx.z;
  int n0 = blockIdx.x * 128;
  int o0 = blockIdx.y * 128;
  int t = threadIdx.x;
  int lane = t & 63;
  int w = __builtin_amdgcn_readfirstlane(t >> 6);
  int mhalf = (w & 1) * 64, nhalf = (w >> 1) * 64;
  const unsigned short* Xb = X + (size_t)b * NPTS * CIN;

  f32x4 acc[4][4] = {};
  int rA = lane >> 2;
  int cofs = (lane & 3) * 8;

  for (int k0 = 0; k0 < CIN; k0 += 32) {
#pragma unroll
    for (int q = 0; q < 2; q++) {
      int r0 = w * 32 + q * 16;
      const unsigned short* ga = A + (size_t)(o0 + r0 + rA) * CIN + k0 + cofs;
      __builtin_amdgcn_global_load_lds(
          (const __attribute__((address_space(1))) void*)ga,
          (__attribute__((address_space(3))) void*)(As + r0 * 32), 16, 0, 0);
      const unsigned short* gb = Xb + (size_t)(n0 + r0 + rA) * CIN + k0 + cofs;
      __builtin_amdgcn_global_load_lds(
          (const __attribute__((address_space(1))) void*)gb,
          (__attribute__((address_space(3))) void*)(Bs + r0 * 32), 16, 0, 0);
    }
    __syncthreads();

    bf16x8 af[4], bfr[4];
    int mi = lane & 15, kq = (lane >> 4) * 8;
#pragma unroll
    for (int i = 0; i < 4; i++) {
      af[i]  = *(const bf16x8*)(As + (mhalf + i * 16 + mi) * 32 + kq);
      bfr[i] = *(const bf16x8*)(Bs + (nhalf + i * 16 + mi) * 32 + kq);
    }
#pragma unroll
    for (int mt = 0; mt < 4; mt++)
#pragma unroll
      for (int nt = 0; nt < 4; nt++)
        acc[mt][nt] = __builtin_amdgcn_mfma_f32_16x16x32_bf16(
            af[mt], bfr[nt], acc[mt][nt], 0, 0, 0);
    __syncthreads();
  }

  // epilogue: transposed write (r-index is m-contiguous -> ushort4 per (mt,nt))
  int mi = lane & 15;
  int rq = (lane >> 4) * 4;
  unsigned short* Xo = X1 + (size_t)b * NPTS * H0;
  int pidx = (b * 64 + blockIdx.x) * 2 + (w >> 1);
#pragma unroll
  for (int mt = 0; mt < 4; mt++) {
    int mbase = o0 + mhalf + mt * 16 + rq;
    float4 bv = *(const float4*)&bias[mbase];
    float sv[4] = {0.f, 0.f, 0.f, 0.f}, sq[4] = {0.f, 0.f, 0.f, 0.f};
#pragma unroll
    for (int nt = 0; nt < 4; nt++) {
      int n = n0 + nhalf + nt * 16 + mi;
      float v0 = acc[mt][nt][0] + bv.x;
      float v1 = acc[mt][nt][1] + bv.y;
      float v2 = acc[mt][nt][2] + bv.z;
      float v3 = acc[mt][nt][3] + bv.w;
      ushort4 o;
      o.x = f2bf(v0); o.y = f2bf(v1); o.z = f2bf(v2); o.w = f2bf(v3);
      *(ushort4*)&Xo[(size_t)n * H0 + mbase] = o;
      sv[0] += v0; sq[0] += v0 * v0;
      sv[1] += v1; sq[1] += v1 * v1;
      sv[2] += v2; sq[2] += v2 * v2;
      sv[3] += v3; sq[3] += v3 * v3;
    }
#pragma unroll
    for (int r = 0; r < 4; r++) {
#pragma unroll
      for (int msk = 1; msk < 16; msk <<= 1) {
        sv[r] += __shfl_xor(sv[r], msk);
        sq[r] += __shfl_xor(sq[r], msk);
      }
    }
    if (mi == 0) {
#pragma unroll
      for (int r = 0; r < 4; r++) {
        gp0s[(size_t)(mbase + r) * NPART + pidx] = sv[r];
        gp0q[(size_t)(mbase + r) * NPART + pidx] = sq[r];
      }
    }
  }
}

// ---------------- finalize partial stats -> a,s ----------------
template <int C>
__global__ __launch_bounds__(64) void fin_kernel(
    const float* __restrict__ gs, const float* __restrict__ gq,
    const float* __restrict__ gamma, const float* __restrict__ beta,
    float* __restrict__ a, float* __restrict__ s) {
  int ch = blockIdx.x * 64 + threadIdx.x;
  const float4* ps = (const float4*)(gs + (size_t)ch * NPART);
  const float4* pq = (const float4*)(gq + (size_t)ch * NPART);
  float sum = 0.f, sq = 0.f;
  for (int p = 0; p < NPART / 4; p++) {
    float4 v = ps[p]; sum += v.x + v.y + v.z + v.w;
    float4 u = pq[p]; sq += u.x + u.y + u.z + u.w;
  }
  const float inv = 1.f / NTOTF;
  float mean = sum * inv;
  float var = sq * inv - mean * mean;
  float ia = gamma[ch] * rsqrtf(var + 1e-5f);
  a[ch] = ia;
  s[ch] = beta[ch] - mean * ia;
}

// ---------------- BN0+ReLU elementwise in-place on X1 (B,N,H0) bf16 ----------------
__global__ __launch_bounds__(256) void bnrelu_kernel(
    unsigned short* __restrict__ X1, const float* __restrict__ a,
    const float* __restrict__ s) {
  size_t base = ((size_t)blockIdx.x * 256 + threadIdx.x) * 8;
  int c = (int)(base & (H0 - 1));
  float4 a0 = *(const float4*)&a[c];
  float4 a1 = *(const float4*)&a[c + 4];
  float4 s0 = *(const float4*)&s[c];
  float4 s1 = *(const float4*)&s[c + 4];
  ushort4 x0 = *(ushort4*)&X1[base];
  ushort4 x1 = *(ushort4*)&X1[base + 4];
  ushort4 o0, o1;
  o0.x = f2bf(fmaxf(bf2f(x0.x) * a0.x + s0.x, 0.f));
  o0.y = f2bf(fmaxf(bf2f(x0.y) * a0.y + s0.y, 0.f));
  o0.z = f2bf(fmaxf(bf2f(x0.z) * a0.z + s0.z, 0.f));
  o0.w = f2bf(fmaxf(bf2f(x0.w) * a0.w + s0.w, 0.f));
  o1.x = f2bf(fmaxf(bf2f(x1.x) * a1.x + s1.x, 0.f));
  o1.y = f2bf(fmaxf(bf2f(x1.y) * a1.y + s1.y, 0.f));
  o1.z = f2bf(fmaxf(bf2f(x1.z) * a1.z + s1.z, 0.f));
  o1.w = f2bf(fmaxf(bf2f(x1.w) * a1.w + s1.w, 0.f));
  *(ushort4*)&X1[base] = o0;
  *(ushort4*)&X1[base + 4] = o1;
}

// ---------------- GEMM2: fp32 out (B,H1,N) + partial stats (stores, no atomics) ----------------
__global__ __launch_bounds__(256) void gemm2_kernel(
    const unsigned short* __restrict__ A, const unsigned short* __restrict__ X,
    const float* __restrict__ bias, float* __restrict__ Y,
    float* __restrict__ gp1s, float* __restrict__ gp1q) {
  __shared__ unsigned short As[128 * 32];
  __shared__ unsigned short Bs[128 * 32];
  int b = blockIdx.z;
  int n0 = blockIdx.x * 128;
  int t = threadIdx.x;
  int lane = t & 63;
  int w = __builtin_amdgcn_readfirstlane(t >> 6);
  int mhalf = (w & 1) * 64, nhalf = (w >> 1) * 64;
  const unsigned short* Xb = X + (size_t)b * NPTS * H0;

  f32x4 acc[4][4] = {};
  int rA = lane >> 2;
  int cofs = (lane & 3) * 8;

  for (int k0 = 0; k0 < H0; k0 += 32) {
#pragma unroll
    for (int q = 0; q < 2; q++) {
      int r0 = w * 32 + q * 16;
      const unsigned short* ga = A + (size_t)(r0 + rA) * H0 + k0 + cofs;
      __builtin_amdgcn_global_load_lds(
          (const __attribute__((address_space(1))) void*)ga,
          (__attribute__((address_space(3))) void*)(As + r0 * 32), 16, 0, 0);
      const unsigned short* gb = Xb + (size_t)(n0 + r0 + rA) * H0 + k0 + cofs;
      __builtin_amdgcn_global_load_lds(
          (const __attribute__((address_space(1))) void*)gb,
          (__attribute__((address_space(3))) void*)(Bs + r0 * 32), 16, 0, 0);
    }
    __syncthreads();

    bf16x8 af[4], bfr[4];
    int mi = lane & 15, kq = (lane >> 4) * 8;
#pragma unroll
    for (int i = 0; i < 4; i++) {
      af[i]  = *(const bf16x8*)(As + (mhalf + i * 16 + mi) * 32 + kq);
      bfr[i] = *(const bf16x8*)(Bs + (nhalf + i * 16 + mi) * 32 + kq);
    }
#pragma unroll
    for (int mt = 0; mt < 4; mt++)
#pragma unroll
      for (int nt = 0; nt < 4; nt++)
        acc[mt][nt] = __builtin_amdgcn_mfma_f32_16x16x32_bf16(
            af[mt], bfr[nt], acc[mt][nt], 0, 0, 0);
    __syncthreads();
  }

  int mi = lane & 15;
  int rq = (lane >> 4) * 4;
  float* Yb = Y + (size_t)b * H1 * NPTS;
  int pidx = (b * 64 + blockIdx.x) * 2 + (w >> 1);
#pragma unroll
  for (int mt = 0; mt < 4; mt++) {
    int mbase = mhalf + mt * 16 + rq;
    float4 bv = *(const float4*)&bias[mbase];
    float sv[4] = {0.f, 0.f, 0.f, 0.f}, sq[4] = {0.f, 0.f, 0.f, 0.f};
#pragma unroll
    for (int nt = 0; nt < 4; nt++) {
      int n = n0 + nhalf + nt * 16 + mi;
      float v0 = acc[mt][nt][0] + bv.x;
      float v1 = acc[mt][nt][1] + bv.y;
      float v2 = acc[mt][nt][2] + bv.z;
      float v3 = acc[mt][nt][3] + bv.w;
      Yb[(size_t)(mbase + 0) * NPTS + n] = v0;
      Yb[(size_t)(mbase + 1) * NPTS + n] = v1;
      Yb[(size_t)(mbase + 2) * NPTS + n] = v2;
      Yb[(size_t)(mbase + 3) * NPTS + n] = v3;
      sv[0] += v0; sq[0] += v0 * v0;
      sv[1] += v1; sq[1] += v1 * v1;
      sv[2] += v2; sq[2] += v2 * v2;
      sv[3] += v3; sq[3] += v3 * v3;
    }
#pragma unroll
    for (int r = 0; r < 4; r++) {
#pragma unroll
      for (int msk = 1; msk < 16; msk <<= 1) {
        sv[r] += __shfl_xor(sv[r], msk);
        sq[r] += __shfl_xor(sq[r], msk);
      }
    }
    if (mi == 0) {
#pragma unroll
      for (int r = 0; r < 4; r++) {
        gp1s[(size_t)(mbase + r) * NPART + pidx] = sv[r];
        gp1q[(size_t)(mbase + r) * NPART + pidx] = sq[r];
      }
    }
  }
}

// ---------------- final BN+ReLU in-place on d_out ----------------
__global__ __launch_bounds__(256) void bn_apply_kernel(
    float* __restrict__ Y, const float* __restrict__ a, const float* __restrict__ s) {
  int idx = blockIdx.x * 256 + threadIdx.x;
  int i = idx * 4;
  int c = (i >> 13) & (H1 - 1);
  float ia = a[c], sh = s[c];
  float4 v = *(float4*)(Y + i);
  v.x = fmaxf(v.x * ia + sh, 0.f);
  v.y = fmaxf(v.y * ia + sh, 0.f);
  v.z = fmaxf(v.z * ia + sh, 0.f);
  v.w = fmaxf(v.w * ia + sh, 0.f);
  *(float4*)(Y + i) = v;
}

extern "C" void kernel_launch(void* const* d_in, const int* in_sizes, int n_in,
                              void* d_out, int out_size, void* d_ws, size_t ws_size,
                              hipStream_t stream) {
  const float* xyz1    = (const float*)d_in[0];
  const float* xyz2    = (const float*)d_in[1];
  const float* points1 = (const float*)d_in[2];
  const float* points2 = (const float*)d_in[3];
  const float* w0      = (const float*)d_in[4];
  const float* b0      = (const float*)d_in[5];
  const float* gamma0  = (const float*)d_in[6];
  const float* beta0   = (const float*)d_in[7];
  const float* w1      = (const float*)d_in[8];
  const float* b1      = (const float*)d_in[9];
  const float* gamma1  = (const float*)d_in[10];
  const float* beta1   = (const float*)d_in[11];
  float* out = (float*)d_out;

  char* ws = (char*)d_ws;
  unsigned short* p2tb = (unsigned short*)ws;  ws += (size_t)BATCH * SPTS * C2 * 2;   // 4.2 MB
  unsigned short* Xp = (unsigned short*)ws;    ws += (size_t)BATCH * NPTS * CIN * 2;  // 25.2 MB
  unsigned short* X1 = (unsigned short*)ws;    ws += (size_t)BATCH * NPTS * H0 * 2;   // 16.8 MB
  unsigned short* Wp = (unsigned short*)ws;    ws += (size_t)(H0 * CIN + H1 * H0) * 2;
  int* nidx = (int*)ws;                        ws += (size_t)BATCH * NPTS * 3 * 4;
  float* nw = (float*)ws;                      ws += (size_t)BATCH * NPTS * 3 * 4;
  float4* xyz2p = (float4*)(((uintptr_t)ws + 15) & ~(uintptr_t)15);
  ws = (char*)xyz2p + (size_t)BATCH * SPTS * 16;
  float* gp0s = (float*)ws;                    ws += (size_t)H0 * NPART * 4;   // 512 KB
  float* gp0q = (float*)ws;                    ws += (size_t)H0 * NPART * 4;
  float* gp1s = (float*)ws;                    ws += (size_t)H1 * NPART * 4;   // 256 KB
  float* gp1q = (float*)ws;                    ws += (size_t)H1 * NPART * 4;
  float* a0 = (float*)ws;                      ws += 1024;
  float* s0 = (float*)ws;                      ws += 1024;
  float* a1 = (float*)ws;                      ws += 1024;
  float* s1 = (float*)ws;                      ws += 1024;
  (void)ws_size; (void)in_sizes; (void)n_in; (void)out_size;

  prep_kernel<<<dim3(1184), 256, 0, stream>>>(points2, p2tb, xyz2, xyz2p,
                                              w0, w1, Wp, points1, Xp);
  knn_kernel<<<dim3(NPTS / 64, BATCH), 1024, 0, stream>>>(xyz1, xyz2p, nidx, nw);
  interp_kernel<<<dim3(BATCH * NPTS / 8), 256, 0, stream>>>(p2tb, nidx, nw, Xp);

  gemm1_kernel<<<dim3(NPTS / 128, H0 / 128, BATCH), 256, 0, stream>>>(
      Wp, Xp, b0, X1, gp0s, gp0q);
  fin_kernel<H0><<<dim3(H0 / 64), 64, 0, stream>>>(gp0s, gp0q, gamma0, beta0, a0, s0);
  bnrelu_kernel<<<dim3((int)((size_t)BATCH * NPTS * H0 / 2048)), 256, 0, stream>>>(X1, a0, s0);
  gemm2_kernel<<<dim3(NPTS / 128, 1, BATCH), 256, 0, stream>>>(
      Wp + H0 * CIN, X1, b1, out, gp1s, gp1q);
  fin_kernel<H1><<<dim3(H1 / 64), 64, 0, stream>>>(gp1s, gp1q, gamma1, beta1, a1, s1);
  bn_apply_kernel<<<dim3(BATCH * H1 * NPTS / 1024), 256, 0, stream>>>(out, a1, s1);
}

// Round 10
// 198.456 us; speedup vs baseline: 1.5971x; 1.0267x over previous
//
#include <hip/hip_runtime.h>
#include <hip/hip_bf16.h>

#define BATCH 4
#define NPTS  8192
#define SPTS  2048
#define C1    128
#define C2    256
#define CIN   384   // C1+C2
#define H0    256
#define H1    128
#define NTOTF 32768.0f  // BATCH*NPTS
#define NPART 512       // stat partials per channel: b(4) x nx(64) x nhalf(2)

typedef __attribute__((ext_vector_type(8))) short bf16x8;
typedef __attribute__((ext_vector_type(4))) float f32x4;

__device__ __forceinline__ unsigned short f2bf(float x) {
  union { float f; unsigned u; } v; v.f = x;
  unsigned r = v.u + 0x7fff + ((v.u >> 16) & 1);   // RNE
  return (unsigned short)(r >> 16);
}
__device__ __forceinline__ float bf2f(unsigned short u) {
  union { unsigned u; float f; } v; v.u = ((unsigned)u) << 16; return v.f;
}

// ---------------- fused prep ----------------
// [0,512):    transpose points2 (B,C2,S) fp32 -> p2tb (B,S,C2) bf16
// [512,1024): pack points1 (B,C1,N) fp32 -> Xp[b][n][0..127] bf16 (stride CIN)
// [1024,1056): prepack xyz2 -> float4 (x,y,z,|c|^2)
// [1056,1184): weights fp32 -> bf16
__global__ __launch_bounds__(256) void prep_kernel(
    const float* __restrict__ p2, unsigned short* __restrict__ p2tb,
    const float* __restrict__ xyz2, float4* __restrict__ xp,
    const float* __restrict__ w0, const float* __restrict__ w1,
    unsigned short* __restrict__ Wp,
    const float* __restrict__ p1, unsigned short* __restrict__ Xp) {
  __shared__ unsigned short shmem[64 * 136];
  int bid = blockIdx.x;
  int t = threadIdx.x;

  if (bid < 512) {  // ---- transpose p2 -> bf16 ----
    int b = bid >> 7, rem = bid & 127;
    int s0 = (rem >> 2) * 64, c0 = (rem & 3) * 64;
    const float* src = p2 + (size_t)b * C2 * SPTS;
    int ss = t & 63, cseg = t >> 6;
#pragma unroll
    for (int i = 0; i < 16; i++) {
      int cc = cseg + i * 4;
      shmem[ss * 72 + cc] = f2bf(src[(size_t)(c0 + cc) * SPTS + s0 + ss]);
    }
    __syncthreads();
    int s = t >> 2, chunk = t & 3;
    uint4 v0 = *(const uint4*)&shmem[s * 72 + chunk * 16];
    uint4 v1 = *(const uint4*)&shmem[s * 72 + chunk * 16 + 8];
    unsigned short* dst = p2tb + (size_t)b * SPTS * C2 + (size_t)(s0 + s) * C2 + c0 + chunk * 16;
    *(uint4*)dst = v0;
    *(uint4*)(dst + 8) = v1;
  } else if (bid < 1024) {  // ---- pack p1 -> Xp[...][0..C1) (stride CIN) ----
    int b2 = bid - 512;
    int b = b2 >> 7, n0 = (b2 & 127) * 64;
    int nn = t & 63, c4 = t >> 6;
#pragma unroll
    for (int i = 0; i < 32; i++) {
      int c = i * 4 + c4;
      shmem[nn * 136 + c] = f2bf(p1[((size_t)b * C1 + c) * NPTS + n0 + nn]);
    }
    __syncthreads();
    int n = t >> 2;
#pragma unroll
    for (int j = 0; j < 4; j++) {
      int ch = (t & 3) + j * 4;
      uint4 v = *(const uint4*)&shmem[n * 136 + ch * 8];
      *(uint4*)&Xp[((size_t)b * NPTS + n0 + n) * CIN + ch * 8] = v;
    }
  } else if (bid < 1056) {  // ---- prepack xyz2 ----
    int idx = (bid - 1024) * 256 + t;
    int b = idx >> 11, s = idx & (SPTS - 1);
    const float* x2 = xyz2 + (size_t)b * 3 * SPTS;
    float x = x2[s], y = x2[SPTS + s], z = x2[2 * SPTS + s];
    xp[idx] = make_float4(x, y, z, x * x + y * y + z * z);
  } else {  // ---- pack weights ----
    int idx = ((bid - 1056) * 256 + t) * 4;
    const float* src = (idx < H0 * CIN) ? (w0 + idx) : (w1 + (idx - H0 * CIN));
    float4 v = *(const float4*)src;
    ushort4 o;
    o.x = f2bf(v.x); o.y = f2bf(v.y); o.z = f2bf(v.z); o.w = f2bf(v.w);
    *(ushort4*)(Wp + idx) = o;
  }
}

#define INS3(d, s, e0, e1, e2, j0, j1, j2)                        \
  {                                                               \
    bool lt0 = (d) < (e0), lt1 = (d) < (e1), lt2 = (d) < (e2);    \
    j2 = lt1 ? (j1) : (lt2 ? (s) : (j2));                         \
    j1 = lt0 ? (j0) : (lt1 ? (s) : (j1));                         \
    j0 = lt0 ? (s) : (j0);                                        \
    e2 = __builtin_amdgcn_fmed3f((d), (e1), (e2));                \
    e1 = __builtin_amdgcn_fmed3f((d), (e0), (e1));                \
    e0 = fminf((d), (e0));                                        \
  }

// ---------------- 3-NN search: 16 waves/block, 128-cand chunks, 2-stage merge ----------------
__global__ __launch_bounds__(1024) void knn_kernel(
    const float* __restrict__ xyz1, const float4* __restrict__ xp,
    int* __restrict__ nidx, float* __restrict__ nw) {
  int b = blockIdx.y;
  int t = threadIdx.x;
  int lane = t & 63;
  int w = __builtin_amdgcn_readfirstlane(t >> 6);
  int n = blockIdx.x * 64 + lane;
  const float* x1 = xyz1 + (size_t)b * 3 * NPTS;
  float px = x1[n], py = x1[NPTS + n], pz = x1[2 * NPTS + n];

  const int CHUNK = SPTS / 16;
  int sbase = w * CHUNK;
  const float4* cp = xp + (size_t)b * SPTS + sbase;

  float d0 = 3e38f, d1 = 3e38f, d2 = 3e38f;
  int i0 = 0, i1 = 0, i2 = 0;
#pragma unroll 8
  for (int j = 0; j < CHUNK; j++) {
    float4 c = cp[j];
    float qc = fmaf(py, c.y, px * c.x);
    qc = fmaf(pz, c.z, qc);
    float d = fmaf(-2.f, qc, c.w);
    int s = sbase + j;
    INS3(d, s, d0, d1, d2, i0, i1, i2);
  }

  __shared__ float dsh[16][64][3];
  __shared__ int   ish[16][64][3];
  dsh[w][lane][0] = d0; dsh[w][lane][1] = d1; dsh[w][lane][2] = d2;
  ish[w][lane][0] = i0; ish[w][lane][1] = i1; ish[w][lane][2] = i2;
  __syncthreads();

  if (t < 256) {
    int g = t >> 6, q = t & 63;
    float e0 = 3e38f, e1 = 3e38f, e2 = 3e38f;
    int j0 = 0, j1 = 0, j2 = 0;
#pragma unroll
    for (int c = 0; c < 4; c++) {
#pragma unroll
      for (int k = 0; k < 3; k++) {
        float d = dsh[4 * g + c][q][k];
        int s = ish[4 * g + c][q][k];
        INS3(d, s, e0, e1, e2, j0, j1, j2);
      }
    }
    dsh[4 * g][q][0] = e0; dsh[4 * g][q][1] = e1; dsh[4 * g][q][2] = e2;
    ish[4 * g][q][0] = j0; ish[4 * g][q][1] = j1; ish[4 * g][q][2] = j2;
  }
  __syncthreads();

  if (t < 64) {
    float e0 = 3e38f, e1 = 3e38f, e2 = 3e38f;
    int j0 = 0, j1 = 0, j2 = 0;
#pragma unroll
    for (int c = 0; c < 4; c++) {
#pragma unroll
      for (int k = 0; k < 3; k++) {
        float d = dsh[4 * c][t][k];
        int s = ish[4 * c][t][k];
        INS3(d, s, e0, e1, e2, j0, j1, j2);
      }
    }
    float qq = px * px + py * py + pz * pz;
    float r0 = 1.f / (e0 + qq + 1e-8f);
    float r1 = 1.f / (e1 + qq + 1e-8f);
    float r2 = 1.f / (e2 + qq + 1e-8f);
    float rs = 1.f / (r0 + r1 + r2);
    int base = (b * NPTS + n) * 3;
    nidx[base + 0] = j0; nidx[base + 1] = j1; nidx[base + 2] = j2;
    nw[base + 0] = r0 * rs; nw[base + 1] = r1 * rs; nw[base + 2] = r2 * rs;
  }
}

// ---------------- interpolation (bf16 gather, standalone) -> Xp[b][n][128..383] ----------------
__global__ __launch_bounds__(256) void interp_kernel(
    const unsigned short* __restrict__ p2tb, const int* __restrict__ nidx,
    const float* __restrict__ nw, unsigned short* __restrict__ Xp) {
  const int PTS = 8;
  int bid = blockIdx.x;
  int b = bid / (NPTS / PTS);
  int p0 = (bid % (NPTS / PTS)) * PTS;
  int c = threadIdx.x;
  const unsigned short* base = p2tb + (size_t)b * SPTS * C2;
#pragma unroll
  for (int k = 0; k < PTS; k++) {
    int p = p0 + k;
    int ib = (b * NPTS + p) * 3;
    int i0 = nidx[ib], i1 = nidx[ib + 1], i2 = nidx[ib + 2];
    float w0v = nw[ib], w1v = nw[ib + 1], w2v = nw[ib + 2];
    float v = w0v * bf2f(base[(size_t)i0 * C2 + c]) +
              w1v * bf2f(base[(size_t)i1 * C2 + c]) +
              w2v * bf2f(base[(size_t)i2 * C2 + c]);
    Xp[((size_t)b * NPTS + p) * CIN + C1 + c] = f2bf(v);
  }
}

// ---------------- GEMM1 (m97 structure, R5-proven): Y0 (B,H0,N) bf16 ----------------
__global__ __launch_bounds__(256) void gemm1_kernel(
    const unsigned short* __restrict__ A, const unsigned short* __restrict__ X,
    const float* __restrict__ bias, unsigned short* __restrict__ Y0) {
  __shared__ unsigned short As[128 * 32];
  __shared__ unsigned short Bs[128 * 32];
  int b = blockIdx.z;
  int n0 = blockIdx.x * 128;
  int o0 = blockIdx.y * 128;
  int t = threadIdx.x;
  int lane = t & 63;
  int w = __builtin_amdgcn_readfirstlane(t >> 6);
  int mhalf = (w & 1) * 64, nhalf = (w >> 1) * 64;
  const unsigned short* Xb = X + (size_t)b * NPTS * CIN;

  f32x4 acc[4][4] = {};
  int rA = lane >> 2;
  int cofs = (lane & 3) * 8;

  for (int k0 = 0; k0 < CIN; k0 += 32) {
#pragma unroll
    for (int q = 0; q < 2; q++) {
      int r0 = w * 32 + q * 16;
      const unsigned short* ga = A + (size_t)(o0 + r0 + rA) * CIN + k0 + cofs;
      __builtin_amdgcn_global_load_lds(
          (const __attribute__((address_space(1))) void*)ga,
          (__attribute__((address_space(3))) void*)(As + r0 * 32), 16, 0, 0);
      const unsigned short* gb = Xb + (size_t)(n0 + r0 + rA) * CIN + k0 + cofs;
      __builtin_amdgcn_global_load_lds(
          (const __attribute__((address_space(1))) void*)gb,
          (__attribute__((address_space(3))) void*)(Bs + r0 * 32), 16, 0, 0);
    }
    __syncthreads();

    bf16x8 af[4], bfr[4];
    int mi = lane & 15, kq = (lane >> 4) * 8;
#pragma unroll
    for (int i = 0; i < 4; i++) {
      af[i]  = *(const bf16x8*)(As + (mhalf + i * 16 + mi) * 32 + kq);
      bfr[i] = *(const bf16x8*)(Bs + (nhalf + i * 16 + mi) * 32 + kq);
    }
#pragma unroll
    for (int mt = 0; mt < 4; mt++)
#pragma unroll
      for (int nt = 0; nt < 4; nt++)
        acc[mt][nt] = __builtin_amdgcn_mfma_f32_16x16x32_bf16(
            af[mt], bfr[nt], acc[mt][nt], 0, 0, 0);
    __syncthreads();
  }

  int mi = lane & 15;
  int rq = (lane >> 4) * 4;
  unsigned short* Yb = Y0 + (size_t)b * H0 * NPTS;
#pragma unroll
  for (int mt = 0; mt < 4; mt++) {
#pragma unroll
    for (int r = 0; r < 4; r++) {
      int m = o0 + mhalf + mt * 16 + rq + r;
      float bv = bias[m];
#pragma unroll
      for (int nt = 0; nt < 4; nt++) {
        int n = n0 + nhalf + nt * 16 + mi;
        Yb[(size_t)m * NPTS + n] = f2bf(acc[mt][nt][r] + bv);
      }
    }
  }
}

// ---------------- BN stats over bf16 (B,C,N) -> a,s (R5-proven) ----------------
template <int C>
__global__ __launch_bounds__(256) void bn_stats_bf16_kernel(
    const unsigned short* __restrict__ Y, const float* __restrict__ gamma,
    const float* __restrict__ beta, float* __restrict__ a, float* __restrict__ s) {
  int o = blockIdx.x;
  int t = threadIdx.x;
  float sum = 0.f, sq = 0.f;
  for (int b = 0; b < BATCH; b++) {
    const unsigned short* p = Y + ((size_t)b * C + o) * NPTS;
    for (int n = t * 4; n < NPTS; n += 1024) {
      ushort4 v = *(const ushort4*)(p + n);
      float x0 = bf2f(v.x), x1 = bf2f(v.y), x2 = bf2f(v.z), x3 = bf2f(v.w);
      sum += x0 + x1 + x2 + x3;
      sq += x0 * x0 + x1 * x1 + x2 * x2 + x3 * x3;
    }
  }
  __shared__ float r1[256], r2[256];
  r1[t] = sum; r2[t] = sq;
  __syncthreads();
  for (int off = 128; off > 0; off >>= 1) {
    if (t < off) { r1[t] += r1[t + off]; r2[t] += r2[t + off]; }
    __syncthreads();
  }
  if (t == 0) {
    float inv = 1.f / NTOTF;
    float mean = r1[0] * inv;
    float var = r2[0] * inv - mean * mean;
    float ia = gamma[o] * rsqrtf(var + 1e-5f);
    a[o] = ia;
    s[o] = beta[o] - mean * ia;
  }
}

// ---------------- BN0 apply + ReLU + transpose (R5-proven) ----------------
__global__ __launch_bounds__(256) void bn0_apply_kernel(
    const unsigned short* __restrict__ Y0, const float* __restrict__ a,
    const float* __restrict__ s, unsigned short* __restrict__ X1) {
  __shared__ unsigned short tile[64][80];
  int b = blockIdx.z, o0 = blockIdx.y * 64, n0 = blockIdx.x * 64;
  int t = threadIdx.x;
  int nn = t & 63, o4 = t >> 6;
#pragma unroll
  for (int i = 0; i < 16; i++) {
    int o = i * 4 + o4;
    float v = bf2f(Y0[((size_t)b * H0 + o0 + o) * NPTS + n0 + nn]);
    v = fmaxf(v * a[o0 + o] + s[o0 + o], 0.f);
    tile[nn][o] = f2bf(v);
  }
  __syncthreads();
  int n = t >> 2;
#pragma unroll
  for (int j = 0; j < 2; j++) {
    int ch = (t & 3) + j * 4;
    uint4 v = *(const uint4*)&tile[n][ch * 8];
    *(uint4*)&X1[((size_t)b * NPTS + n0 + n) * H0 + o0 + ch * 8] = v;
  }
}

// ---------------- GEMM2: fp32 out (B,H1,N) + partial stats (plain stores; R8-proven) ----------------
__global__ __launch_bounds__(256) void gemm2_kernel(
    const unsigned short* __restrict__ A, const unsigned short* __restrict__ X,
    const float* __restrict__ bias, float* __restrict__ Y,
    float* __restrict__ gp1s, float* __restrict__ gp1q) {
  __shared__ unsigned short As[128 * 32];
  __shared__ unsigned short Bs[128 * 32];
  int b = blockIdx.z;
  int n0 = blockIdx.x * 128;
  int t = threadIdx.x;
  int lane = t & 63;
  int w = __builtin_amdgcn_readfirstlane(t >> 6);
  int mhalf = (w & 1) * 64, nhalf = (w >> 1) * 64;
  const unsigned short* Xb = X + (size_t)b * NPTS * H0;

  f32x4 acc[4][4] = {};
  int rA = lane >> 2;
  int cofs = (lane & 3) * 8;

  for (int k0 = 0; k0 < H0; k0 += 32) {
#pragma unroll
    for (int q = 0; q < 2; q++) {
      int r0 = w * 32 + q * 16;
      const unsigned short* ga = A + (size_t)(r0 + rA) * H0 + k0 + cofs;
      __builtin_amdgcn_global_load_lds(
          (const __attribute__((address_space(1))) void*)ga,
          (__attribute__((address_space(3))) void*)(As + r0 * 32), 16, 0, 0);
      const unsigned short* gb = Xb + (size_t)(n0 + r0 + rA) * H0 + k0 + cofs;
      __builtin_amdgcn_global_load_lds(
          (const __attribute__((address_space(1))) void*)gb,
          (__attribute__((address_space(3))) void*)(Bs + r0 * 32), 16, 0, 0);
    }
    __syncthreads();

    bf16x8 af[4], bfr[4];
    int mi = lane & 15, kq = (lane >> 4) * 8;
#pragma unroll
    for (int i = 0; i < 4; i++) {
      af[i]  = *(const bf16x8*)(As + (mhalf + i * 16 + mi) * 32 + kq);
      bfr[i] = *(const bf16x8*)(Bs + (nhalf + i * 16 + mi) * 32 + kq);
    }
#pragma unroll
    for (int mt = 0; mt < 4; mt++)
#pragma unroll
      for (int nt = 0; nt < 4; nt++)
        acc[mt][nt] = __builtin_amdgcn_mfma_f32_16x16x32_bf16(
            af[mt], bfr[nt], acc[mt][nt], 0, 0, 0);
    __syncthreads();
  }

  int mi = lane & 15;
  int rq = (lane >> 4) * 4;
  float* Yb = Y + (size_t)b * H1 * NPTS;
  int pidx = (b * 64 + blockIdx.x) * 2 + (w >> 1);
#pragma unroll
  for (int mt = 0; mt < 4; mt++) {
    int mbase = mhalf + mt * 16 + rq;
    float4 bv = *(const float4*)&bias[mbase];
    float sv[4] = {0.f, 0.f, 0.f, 0.f}, sq[4] = {0.f, 0.f, 0.f, 0.f};
#pragma unroll
    for (int nt = 0; nt < 4; nt++) {
      int n = n0 + nhalf + nt * 16 + mi;
      float v0 = acc[mt][nt][0] + bv.x;
      float v1 = acc[mt][nt][1] + bv.y;
      float v2 = acc[mt][nt][2] + bv.z;
      float v3 = acc[mt][nt][3] + bv.w;
      Yb[(size_t)(mbase + 0) * NPTS + n] = v0;
      Yb[(size_t)(mbase + 1) * NPTS + n] = v1;
      Yb[(size_t)(mbase + 2) * NPTS + n] = v2;
      Yb[(size_t)(mbase + 3) * NPTS + n] = v3;
      sv[0] += v0; sq[0] += v0 * v0;
      sv[1] += v1; sq[1] += v1 * v1;
      sv[2] += v2; sq[2] += v2 * v2;
      sv[3] += v3; sq[3] += v3 * v3;
    }
#pragma unroll
    for (int r = 0; r < 4; r++) {
#pragma unroll
      for (int msk = 1; msk < 16; msk <<= 1) {
        sv[r] += __shfl_xor(sv[r], msk);
        sq[r] += __shfl_xor(sq[r], msk);
      }
    }
    if (mi == 0) {
#pragma unroll
      for (int r = 0; r < 4; r++) {
        gp1s[(size_t)(mbase + r) * NPART + pidx] = sv[r];
        gp1q[(size_t)(mbase + r) * NPART + pidx] = sq[r];
      }
    }
  }
}

// ---------------- finalize partial stats -> a,s (R8-proven) ----------------
__global__ __launch_bounds__(64) void fin_kernel(
    const float* __restrict__ gs, const float* __restrict__ gq,
    const float* __restrict__ gamma, const float* __restrict__ beta,
    float* __restrict__ a, float* __restrict__ s) {
  int ch = blockIdx.x * 64 + threadIdx.x;
  const float4* ps = (const float4*)(gs + (size_t)ch * NPART);
  const float4* pq = (const float4*)(gq + (size_t)ch * NPART);
  float sum = 0.f, sq = 0.f;
  for (int p = 0; p < NPART / 4; p++) {
    float4 v = ps[p]; sum += v.x + v.y + v.z + v.w;
    float4 u = pq[p]; sq += u.x + u.y + u.z + u.w;
  }
  const float inv = 1.f / NTOTF;
  float mean = sum * inv;
  float var = sq * inv - mean * mean;
  float ia = gamma[ch] * rsqrtf(var + 1e-5f);
  a[ch] = ia;
  s[ch] = beta[ch] - mean * ia;
}

// ---------------- final BN+ReLU in-place on d_out ----------------
__global__ __launch_bounds__(256) void bn_apply_kernel(
    float* __restrict__ Y, const float* __restrict__ a, const float* __restrict__ s) {
  int idx = blockIdx.x * 256 + threadIdx.x;
  int i = idx * 4;
  int c = (i >> 13) & (H1 - 1);
  float ia = a[c], sh = s[c];
  float4 v = *(float4*)(Y + i);
  v.x = fmaxf(v.x * ia + sh, 0.f);
  v.y = fmaxf(v.y * ia + sh, 0.f);
  v.z = fmaxf(v.z * ia + sh, 0.f);
  v.w = fmaxf(v.w * ia + sh, 0.f);
  *(float4*)(Y + i) = v;
}

extern "C" void kernel_launch(void* const* d_in, const int* in_sizes, int n_in,
                              void* d_out, int out_size, void* d_ws, size_t ws_size,
                              hipStream_t stream) {
  const float* xyz1    = (const float*)d_in[0];
  const float* xyz2    = (const float*)d_in[1];
  const float* points1 = (const float*)d_in[2];
  const float* points2 = (const float*)d_in[3];
  const float* w0      = (const float*)d_in[4];
  const float* b0      = (const float*)d_in[5];
  const float* gamma0  = (const float*)d_in[6];
  const float* beta0   = (const float*)d_in[7];
  const float* w1      = (const float*)d_in[8];
  const float* b1      = (const float*)d_in[9];
  const float* gamma1  = (const float*)d_in[10];
  const float* beta1   = (const float*)d_in[11];
  float* out = (float*)d_out;

  char* ws = (char*)d_ws;
  unsigned short* p2tb = (unsigned short*)ws;  ws += (size_t)BATCH * SPTS * C2 * 2;   // 4.2 MB
  unsigned short* Xp = (unsigned short*)ws;    ws += (size_t)BATCH * NPTS * CIN * 2;  // 25.2 MB
  unsigned short* Y0 = (unsigned short*)ws;    ws += (size_t)BATCH * H0 * NPTS * 2;   // 16.8 MB
  unsigned short* X1 = (unsigned short*)ws;    ws += (size_t)BATCH * NPTS * H0 * 2;   // 16.8 MB
  unsigned short* Wp = (unsigned short*)ws;    ws += (size_t)(H0 * CIN + H1 * H0) * 2;
  int* nidx = (int*)ws;                        ws += (size_t)BATCH * NPTS * 3 * 4;
  float* nw = (float*)ws;                      ws += (size_t)BATCH * NPTS * 3 * 4;
  float4* xyz2p = (float4*)(((uintptr_t)ws + 15) & ~(uintptr_t)15);
  ws = (char*)xyz2p + (size_t)BATCH * SPTS * 16;
  float* gp1s = (float*)ws;                    ws += (size_t)H1 * NPART * 4;   // 256 KB
  float* gp1q = (float*)ws;                    ws += (size_t)H1 * NPART * 4;
  float* a0 = (float*)ws;                      ws += 1024;
  float* s0 = (float*)ws;                      ws += 1024;
  float* a1 = (float*)ws;                      ws += 1024;
  float* s1 = (float*)ws;                      ws += 1024;
  (void)ws_size; (void)in_sizes; (void)n_in; (void)out_size;

  prep_kernel<<<dim3(1184), 256, 0, stream>>>(points2, p2tb, xyz2, xyz2p,
                                              w0, w1, Wp, points1, Xp);
  knn_kernel<<<dim3(NPTS / 64, BATCH), 1024, 0, stream>>>(xyz1, xyz2p, nidx, nw);
  interp_kernel<<<dim3(BATCH * NPTS / 8), 256, 0, stream>>>(p2tb, nidx, nw, Xp);

  gemm1_kernel<<<dim3(NPTS / 128, H0 / 128, BATCH), 256, 0, stream>>>(Wp, Xp, b0, Y0);
  bn_stats_bf16_kernel<H0><<<H0, 256, 0, stream>>>(Y0, gamma0, beta0, a0, s0);
  bn0_apply_kernel<<<dim3(NPTS / 64, H0 / 64, BATCH), 256, 0, stream>>>(Y0, a0, s0, X1);
  gemm2_kernel<<<dim3(NPTS / 128, 1, BATCH), 256, 0, stream>>>(
      Wp + H0 * CIN, X1, b1, out, gp1s, gp1q);
  fin_kernel<<<dim3(H1 / 64), 64, 0, stream>>>(gp1s, gp1q, gamma1, beta1, a1, s1);
  bn_apply_kernel<<<dim3(BATCH * H1 * NPTS / 1024), 256, 0, stream>>>(out, a1, s1);
}